// Round 19
// baseline (138.486 us; speedup 1.0000x reference)
//
#include <hip/hip_runtime.h>
#include <hip/hip_bf16.h>

#define BATCH   4
#define NBOX    8192
#define BLOCK   256
#define TSZ     256                  // tile size (rows & cols)
#define NT      (NBOX / TSZ)         // 32 tiles per batch
#define NPAIRS  (NT * (NT + 1) / 2)  // 528 tile-pairs per batch
#define NBINS   2048
#define SUBS    8                    // sub-slices per batch for the sort
#define SUBSZ   (NBOX / SUBS)        // 1024 boxes per slice
#define STH     512                  // sort kernel threads

__device__ __forceinline__ float bf2f(unsigned short u) {
    union { unsigned int i; float f; } c;
    c.i = ((unsigned int)u) << 16;
    return c.f;
}

__device__ __forceinline__ bool box_plausible(float x1, float y1, float x2, float y2) {
    bool ok = (x1 == x1) && (y1 == y1) && (x2 == x2) && (y2 == y2);
    ok = ok && fabsf(x1) < 1e4f && fabsf(y1) < 1e4f && fabsf(x2) < 1e4f && fabsf(y2) < 1e4f;
    ok = ok && x1 >= -1.0f && x1 <= 300.0f && y1 >= -1.0f && y1 <= 300.0f;
    const float w = x2 - x1, h = y2 - y1;
    ok = ok && w >= -0.1f && w <= 80.0f && h >= -0.1f && h <= 80.0f;
    return ok;
}

// Wave-redundant dtype probe; all waves deterministically agree. true -> f32.
__device__ __forceinline__ bool wave_probe_is_f32(const void* boxes_raw) {
    const int lane = threadIdx.x & 63;
    const float* bf = (const float*)boxes_raw;
    const bool okf = box_plausible(bf[lane * 4 + 0], bf[lane * 4 + 1],
                                   bf[lane * 4 + 2], bf[lane * 4 + 3]);
    const unsigned short* bh = (const unsigned short*)boxes_raw;
    const bool okh = box_plausible(bf2f(bh[lane * 4 + 0]), bf2f(bh[lane * 4 + 1]),
                                   bf2f(bh[lane * 4 + 2]), bf2f(bh[lane * 4 + 3]));
    const unsigned long long mf = __ballot(okf);
    const unsigned long long mh = __ballot(okh);
    return __popcll(mf) >= __popcll(mh);
}

__device__ __forceinline__ float4 load_box(const void* boxes_raw, size_t idx, bool isf32) {
    if (isf32) {
        return reinterpret_cast<const float4*>(boxes_raw)[idx];
    } else {
        const ushort4 u = reinterpret_cast<const ushort4*>(boxes_raw)[idx];
        return make_float4(bf2f(u.x), bf2f(u.y), bf2f(u.z), bf2f(u.w));
    }
}

__device__ __forceinline__ float load_score(const void* scores_raw, size_t idx, bool isf32) {
    return isf32 ? ((const float*)scores_raw)[idx]
                 : bf2f(((const unsigned short*)scores_raw)[idx]);
}

__device__ __forceinline__ int x1_bin(float x1) {
    const int bb = (int)(x1 * 8.0f);           // 2048 bins over [0,256)
    return min(NBINS - 1, max(0, bb));
}

// exp(-iou/0.5) = exp2(iou * (-2 log2 e)); arg in [-2.886, 0] -> raw v_exp ok
#define CEXP (-2.8853900817779268f)

__device__ __forceinline__ float pair_weight(
    float ix1, float iy1, float ix2, float iy2, float iarea,
    const float4& bj, float jarea)
{
    float w = fminf(ix2, bj.z) - fmaxf(ix1, bj.x);
    float h = fminf(iy2, bj.w) - fmaxf(iy1, bj.y);
    w = fmaxf(w, 0.0f);
    h = fmaxf(h, 0.0f);
    const float inter = w * h;
    const float uni   = iarea + jarea - inter;          // >= ~1 always
    const float arg   = (CEXP * inter) * __builtin_amdgcn_rcpf(uni);
    return __builtin_amdgcn_exp2f(arg);
}

// ---- sort kernel: byte-identical to r15/r18 (measured best) ----
__global__ __launch_bounds__(STH) void sort_kernel(
    const void* __restrict__ boxes_raw, const void* __restrict__ scores_raw,
    float4* __restrict__ sboxes, float* __restrict__ sscores,
    float* __restrict__ adj,                                  // (B,N) zeroed
    float* __restrict__ minx1c, float* __restrict__ maxx2c,   // (B,NT)
    int* __restrict__ pairlist, int* __restrict__ count)      // (B,NPAIRS),(B)
{
    __shared__ int hist[NBINS];          // full-batch counts -> then sex
    __shared__ int bmax[NBINS];          // per-bin max x2 bits
    __shared__ int hist2[NBINS];         // earlier-subs counts -> then loff
    __shared__ int wsum[STH / 64];
    __shared__ float sminT[NT], smaxT[NT];
    __shared__ int scnt;

    const int b    = blockIdx.x / SUBS;
    const int sub  = blockIdx.x % SUBS;
    const int tid  = threadIdx.x;
    const int lane = tid & 63;
    const int wv   = tid >> 6;
    const bool isf32 = wave_probe_is_f32(boxes_raw);
    const size_t base = (size_t)b * NBOX;

#pragma unroll
    for (int i = 0; i < NBINS / STH; i++) {
        hist[i * STH + tid]  = 0;
        bmax[i * STH + tid]  = 0;
        hist2[i * STH + tid] = 0;
    }
    if (tid == 0) scnt = 0;
    {
        const size_t z = (size_t)blockIdx.x * 1024;
        adj[z + tid] = 0.0f;
        adj[z + STH + tid] = 0.0f;
    }
    __syncthreads();

#pragma unroll
    for (int k = 0; k < NBOX / STH; k++) {
        const float4 bx = load_box(boxes_raw, base + k * STH + tid, isf32);
        const int bin = x1_bin(bx.x);
        atomicAdd(&hist[bin], 1);
        atomicMax(&bmax[bin], __float_as_int(bx.z));
    }
    for (int i = tid; i < sub * SUBSZ; i += STH) {
        const float4 bx = load_box(boxes_raw, base + i, isf32);
        atomicAdd(&hist2[x1_bin(bx.x)], 1);
    }
    __syncthreads();

    {
        int tot[4], cum[4];
        int run = 0;
#pragma unroll
        for (int i = 0; i < 4; i++) {
            tot[i] = hist[tid * 4 + i];
            run += tot[i]; cum[i] = run;
        }
        int v = run;
#pragma unroll
        for (int d = 1; d < 64; d <<= 1) {
            const int u = __shfl_up(v, d);
            if (lane >= d) v += u;
        }
        if (lane == 63) wsum[wv] = v;
        __syncthreads();
        int wb = 0;
        for (int w = 0; w < wv; w++) wb += wsum[w];
        const int tb = wb + v - run;
#pragma unroll
        for (int i = 0; i < 4; i++) {
            const int bin = tid * 4 + i;
            const int e = tb + cum[i] - tot[i];
            const int m = hist2[bin];
            hist[bin]  = e;
            hist2[bin] = e + m;
        }
    }
    __syncthreads();

    if (tid < NT) {
        int p = tid * TSZ;
        int lo = 0, hi = NBINS - 1;
        while (lo < hi) { const int mid = (lo + hi + 1) >> 1;
                          if (hist[mid] <= p) lo = mid; else hi = mid - 1; }
        const int Bf = lo;
        p = tid * TSZ + TSZ - 1;
        lo = 0; hi = NBINS - 1;
        while (lo < hi) { const int mid = (lo + hi + 1) >> 1;
                          if (hist[mid] <= p) lo = mid; else hi = mid - 1; }
        const int Bl = lo;
        int mb = 0;
        for (int q = Bf; q <= Bl; q++) mb = max(mb, bmax[q]);
        const float mn = (float)Bf * 0.125f;
        const float mx = __int_as_float(mb);
        sminT[tid] = mn; smaxT[tid] = mx;
        if (sub == 0) {
            minx1c[b * NT + tid] = mn;
            maxx2c[b * NT + tid] = mx;
        }
    }
    __syncthreads();

    if (sub == 0) {
        for (int q = tid; q < NPAIRS; q += STH) {
            int p = q, it = 0;
            while (p >= NT - it) { p -= NT - it; it++; }
            const int jt = it + p;
            const bool live = !((smaxT[it] < sminT[jt]) || (smaxT[jt] < sminT[it]));
            if (live) {
                const int idx = atomicAdd(&scnt, 1);
                pairlist[b * NPAIRS + idx] = (it << 8) | jt;
            }
        }
    }

#pragma unroll
    for (int k = 0; k < SUBSZ / STH; k++) {
        const int i = sub * SUBSZ + k * STH + tid;
        const float4 bx = load_box(boxes_raw, base + i, isf32);
        const float  sc = load_score(scores_raw, base + i, isf32);
        const int pos = atomicAdd(&hist2[x1_bin(bx.x)], 1);
        sboxes[base + pos]  = bx;
        sscores[base + pos] = sc;
    }

    __syncthreads();
    if (sub == 0 && tid == 0) count[b] = scnt;
}

// Inner rotation loop over N live row-bands; DIAG skips the column side.
template<int N, bool DIAG>
__device__ __forceinline__ void run_tloop(
    const float4* sbj, const float2* saj, int wvbase, int lane,
    const float* rx1, const float* ry1, const float* rx2, const float* ry2,
    const float* rar, const float* rsc, float* accr, float& accc)
{
#pragma unroll 2
    for (int t = 0; t < 64; t++) {
        const int idx = wvbase + ((lane + t) & 63);
        const float4 bj = sbj[idx];        // stride-1 window: conflict-free
        const float2 as = saj[idx];
        float c = 0.0f;
#pragma unroll
        for (int q = 0; q < N; q++) {
            const float e = pair_weight(rx1[q], ry1[q], rx2[q], ry2[q], rar[q], bj, as.x);
            accr[q] = fmaf(e, as.y, accr[q]);
            if (!DIAG) c = fmaf(e, rsc[q], c);
        }
        if (!DIAG) accc += __shfl(c, (lane - t) & 63);   // owner lane (lane+t)&63 pulls
    }
}

// adj over live tile-pairs with Y-BAND MASKING: both tiles are y-rank-sorted
// in-block (deterministic, redundant, ~1K cyc/tile); row-band k x col-window
// wv combos that are y-disjoint have weight EXACTLY 1 (h clamps to 0) and
// reduce to closed-form score-sum corrections. Results scatter back through
// the rank permutation so adj[] stays in the x-sorted index space -> sort and
// finish kernels are untouched.
__global__ __launch_bounds__(BLOCK, 4) void soft_nms_adj_kernel(
    const float4* __restrict__ sboxes,   // (B,N) x-sorted f32 boxes
    const float* __restrict__ sscores,   // (B,N) x-sorted f32 scores
    const int* __restrict__ pairlist,    // (B,NPAIRS) compacted live pairs
    const int* __restrict__ count,       // (B)
    float* __restrict__ adj)             // (B,N) f32, zeroed
{
    __shared__ float4 sbi[TSZ];                     // i-tile, y-sorted
    __shared__ float2 sai[TSZ];                     // (area, score)
    __shared__ float4 sbj[TSZ];                     // j-tile, y-sorted
    __shared__ float2 saj[TSZ];
    __shared__ int    permi[TSZ], permj[TSZ];       // sorted pos -> orig in-tile idx
    __shared__ __align__(16) float tmpbuf[1536];    // stage tmp, later srow[4][256]
    __shared__ float ymini[4], ymaxi[4], yminj[4], ymaxj[4], rsumi[4], rsumj[4];

    const int bid = blockIdx.x;
    const int b   = bid / NPAIRS;
    const int p   = bid % NPAIRS;
    if (p >= count[b]) return;            // dead block: one scalar load
    const int pr = pairlist[b * NPAIRS + p];
    const int it = pr >> 8, jt = pr & 255;

    const int tid  = threadIdx.x;
    const int lane = tid & 63;
    const int wv   = tid >> 6;
    const size_t base = (size_t)b * NBOX;

    // ---- stage + y-rank-sort both tiles (deterministic; diag sorts twice, fine)
    {
        float* ytmp = tmpbuf + 1280;
        // i-tile
        {
            const float4 bx = sboxes[base + it * TSZ + tid];
            const float  sc = sscores[base + it * TSZ + tid];
            ytmp[tid] = bx.y;
            __syncthreads();
            int rank = 0;
            const float yt = bx.y;
#pragma unroll 8
            for (int j = 0; j < TSZ; j++) {
                const float yj = ytmp[j];
                rank += (yj < yt) || (yj == yt && j < tid);
            }
            sbi[rank]   = bx;
            sai[rank]   = make_float2((bx.z - bx.x) * (bx.w - bx.y), sc);
            permi[rank] = tid;
            __syncthreads();
        }
        // j-tile
        {
            const float4 bx = sboxes[base + jt * TSZ + tid];
            const float  sc = sscores[base + jt * TSZ + tid];
            ytmp[tid] = bx.y;
            __syncthreads();
            int rank = 0;
            const float yt = bx.y;
#pragma unroll 8
            for (int j = 0; j < TSZ; j++) {
                const float yj = ytmp[j];
                rank += (yj < yt) || (yj == yt && j < tid);
            }
            sbj[rank]   = bx;
            saj[rank]   = make_float2((bx.z - bx.x) * (bx.w - bx.y), sc);
            permj[rank] = tid;
            __syncthreads();
        }
    }

    const int wvbase = wv * 64;

    // ---- per-band meta: wave wv reduces band wv of each tile
    {
        float y2i = sbi[wvbase + lane].w;
        float y2j = sbj[wvbase + lane].w;
        float ssi = sai[wvbase + lane].y;
        float ssj = saj[wvbase + lane].y;
#pragma unroll
        for (int off = 32; off > 0; off >>= 1) {
            y2i = fmaxf(y2i, __shfl_down(y2i, off));
            y2j = fmaxf(y2j, __shfl_down(y2j, off));
            ssi += __shfl_down(ssi, off);
            ssj += __shfl_down(ssj, off);
        }
        if (lane == 0) {
            ymaxi[wv] = y2i; ymaxj[wv] = y2j;
            rsumi[wv] = ssi; rsumj[wv] = ssj;
            ymini[wv] = sbi[wvbase].y;           // sorted: first = min y1
            yminj[wv] = sbj[wvbase].y;
        }
    }
    __syncthreads();

    // ---- wave-uniform y-band mask for this wave's col window wv
    int mask = 0;
    float ccorr = 0.0f;                           // col-side weight-1 correction
#pragma unroll
    for (int k = 0; k < 4; k++) {
        const bool live = (ymini[k] <= ymaxj[wv]) && (yminj[wv] <= ymaxi[k]);
        if (live) mask |= (1 << k);
        else      ccorr += rsumi[k];
    }
    const int nl = __popc(mask);
    int m2 = mask;
    const int l0 = __ffs(m2) - 1; m2 &= m2 - 1;
    const int l1 = __ffs(m2) - 1; m2 &= m2 - 1;
    const int l2 = __ffs(m2) - 1; m2 &= m2 - 1;
    const int l3 = __ffs(m2) - 1;

    // ---- load live row-band slots (static slot regs, dynamic band index)
    float rx1[4], ry1[4], rx2[4], ry2[4], rar[4], rsc[4], accr[4];
    accr[0] = accr[1] = accr[2] = accr[3] = 0.0f;
#define LOADSLOT(q, lk)                                                      \
    if (nl > (q)) {                                                          \
        const int r = (lk) * 64 + lane;                                      \
        const float4 u = sbi[r]; const float2 a = sai[r];                    \
        rx1[q] = u.x; ry1[q] = u.y; rx2[q] = u.z; ry2[q] = u.w;              \
        rar[q] = a.x; rsc[q] = a.y;                                          \
    }
    LOADSLOT(0, l0) LOADSLOT(1, l1) LOADSLOT(2, l2) LOADSLOT(3, l3)
#undef LOADSLOT

    float accc = ccorr;
    if (it != jt) {
        switch (nl) {
            case 4: run_tloop<4,false>(sbj, saj, wvbase, lane, rx1,ry1,rx2,ry2,rar,rsc, accr, accc); break;
            case 3: run_tloop<3,false>(sbj, saj, wvbase, lane, rx1,ry1,rx2,ry2,rar,rsc, accr, accc); break;
            case 2: run_tloop<2,false>(sbj, saj, wvbase, lane, rx1,ry1,rx2,ry2,rar,rsc, accr, accc); break;
            case 1: run_tloop<1,false>(sbj, saj, wvbase, lane, rx1,ry1,rx2,ry2,rar,rsc, accr, accc); break;
            default: break;
        }
        // col side: sorted col wvbase+lane -> original index via permj
        atomicAdd(&adj[base + jt * TSZ + permj[wvbase + lane]], accc);
    } else {
        switch (nl) {
            case 4: run_tloop<4,true>(sbj, saj, wvbase, lane, rx1,ry1,rx2,ry2,rar,rsc, accr, accc); break;
            case 3: run_tloop<3,true>(sbj, saj, wvbase, lane, rx1,ry1,rx2,ry2,rar,rsc, accr, accc); break;
            case 2: run_tloop<2,true>(sbj, saj, wvbase, lane, rx1,ry1,rx2,ry2,rar,rsc, accr, accc); break;
            case 1: run_tloop<1,true>(sbj, saj, wvbase, lane, rx1,ry1,rx2,ry2,rar,rsc, accr, accc); break;
            default: break;
        }
    }

    // ---- row partials: live slots + dead-band weight-1 fills, then combine
    float (*srow)[TSZ] = (float(*)[TSZ])tmpbuf;   // tmp no longer needed
    if (nl > 0) srow[wv][l0 * 64 + lane] = accr[0];
    if (nl > 1) srow[wv][l1 * 64 + lane] = accr[1];
    if (nl > 2) srow[wv][l2 * 64 + lane] = accr[2];
    if (nl > 3) srow[wv][l3 * 64 + lane] = accr[3];
#pragma unroll
    for (int k = 0; k < 4; k++) {
        if (!(mask & (1 << k))) srow[wv][k * 64 + lane] = rsumj[wv];
    }
    __syncthreads();
    {
        const float rs = srow[0][tid] + srow[1][tid] + srow[2][tid] + srow[3][tid];
        atomicAdd(&adj[base + it * TSZ + permi[tid]], rs);  // back to orig index
    }
}

// ---- finish kernel: byte-identical to r15/r18 ----
#define FBLK 1024
__global__ __launch_bounds__(FBLK) void soft_nms_finish_kernel(
    const float4* __restrict__ sboxes,   // (B,N) sorted f32 boxes
    const float* __restrict__ sscores,   // (B,N) sorted f32 scores
    const float* __restrict__ adj,       // (B,N) f32
    const float* __restrict__ minx1c, const float* __restrict__ maxx2c,  // (B,NT)
    const void* __restrict__ boxes_raw,  // only for output-dtype probe
    void* __restrict__ out)              // (B,4) dtype matches input
{
    constexpr int K  = NBOX / FBLK;             // 8 items per thread
    constexpr int NW = FBLK / 64;               // 16 waves
    __shared__ float sminx[NT], smaxx[NT], ssumT[NT], scorr[NT];
    __shared__ float smax_[NW];
    __shared__ float sred[NW][5];

    const int b    = blockIdx.x;
    const int tid  = threadIdx.x;
    const int lane = tid & 63;
    const int wv   = tid >> 6;
    const size_t base = (size_t)b * NBOX;

    const bool isf32 = wave_probe_is_f32(boxes_raw);

    if (tid < NT) {
        sminx[tid] = minx1c[b * NT + tid];
        smaxx[tid] = maxx2c[b * NT + tid];
    }
#pragma unroll
    for (int tt = 0; tt < 2; tt++) {
        const int T = wv * 2 + tt;
        float sm = 0.0f;
#pragma unroll
        for (int q = 0; q < 4; q++) sm += sscores[base + T * TSZ + q * 64 + lane];
#pragma unroll
        for (int off = 32; off > 0; off >>= 1) sm += __shfl_down(sm, off);
        if (lane == 0) ssumT[T] = sm;
    }
    __syncthreads();
    if (tid < NT) {
        float c = 0.0f;
        for (int T2 = 0; T2 < NT; T2++) {
            const bool skip = (smaxx[tid] < sminx[T2]) || (smaxx[T2] < sminx[tid]);
            if (skip) c += ssumT[T2];
        }
        scorr[tid] = c;
    }
    __syncthreads();

    float av[K];
    float m = -3.4e38f;
#pragma unroll
    for (int k = 0; k < K; k++) {
        const int r = k * FBLK + tid;
        av[k] = adj[base + r] + scorr[r >> 8];
        m = fmaxf(m, av[k]);
    }
#pragma unroll
    for (int off = 32; off > 0; off >>= 1)
        m = fmaxf(m, __shfl_down(m, off));
    if (lane == 0) smax_[wv] = m;
    __syncthreads();
    float M = smax_[0];
#pragma unroll
    for (int w = 1; w < NW; w++) M = fmaxf(M, smax_[w]);

    const float L2E = 1.4426950408889634f;
    float es = 0.0f, s0 = 0.0f, s1 = 0.0f, s2 = 0.0f, s3 = 0.0f;
#pragma unroll
    for (int k = 0; k < K; k++) {
        const float e = __builtin_amdgcn_exp2f((av[k] - M) * L2E);
        const float4 u = sboxes[base + k * FBLK + tid];
        es += e;
        s0 += e * u.x;
        s1 += e * u.y;
        s2 += e * u.z;
        s3 += e * u.w;
    }
#pragma unroll
    for (int off = 32; off > 0; off >>= 1) {
        es += __shfl_down(es, off);
        s0 += __shfl_down(s0, off);
        s1 += __shfl_down(s1, off);
        s2 += __shfl_down(s2, off);
        s3 += __shfl_down(s3, off);
    }
    if (lane == 0) {
        sred[wv][0] = es; sred[wv][1] = s0; sred[wv][2] = s1;
        sred[wv][3] = s2; sred[wv][4] = s3;
    }
    __syncthreads();
    if (tid == 0) {
        float ES = 0.0f, o[4] = {0.0f, 0.0f, 0.0f, 0.0f};
#pragma unroll
        for (int w = 0; w < NW; w++) {
            ES   += sred[w][0];
            o[0] += sred[w][1];
            o[1] += sred[w][2];
            o[2] += sred[w][3];
            o[3] += sred[w][4];
        }
        const float inv = 1.0f / ES;
        if (isf32) {
            float* of = (float*)out;
            for (int c = 0; c < 4; c++) of[b * 4 + c] = o[c] * inv;
        } else {
            __hip_bfloat16* oh = (__hip_bfloat16*)out;
            for (int c = 0; c < 4; c++) oh[b * 4 + c] = __float2bfloat16(o[c] * inv);
        }
    }
}

extern "C" void kernel_launch(void* const* d_in, const int* in_sizes, int n_in,
                              void* d_out, int out_size, void* d_ws, size_t ws_size,
                              hipStream_t stream) {
    const void* boxes_raw  = d_in[0];   // (4,8192,4)
    const void* scores_raw = d_in[1];   // (4,8192)

    char* w = (char*)d_ws;
    float4* sboxes   = (float4*)w;                 w += (size_t)BATCH * NBOX * 16;
    float*  sscores  = (float*)w;                  w += (size_t)BATCH * NBOX * 4;
    float*  adj      = (float*)w;                  w += (size_t)BATCH * NBOX * 4;
    float*  minx1c   = (float*)w;                  w += (size_t)BATCH * NT * 4;
    float*  maxx2c   = (float*)w;                  w += (size_t)BATCH * NT * 4;
    int*    pairlist = (int*)w;                    w += (size_t)BATCH * NPAIRS * 4;
    int*    count    = (int*)w;

    sort_kernel<<<dim3(BATCH * SUBS), dim3(STH), 0, stream>>>(
        boxes_raw, scores_raw, sboxes, sscores, adj, minx1c, maxx2c, pairlist, count);
    soft_nms_adj_kernel<<<dim3(BATCH * NPAIRS), dim3(BLOCK), 0, stream>>>(
        sboxes, sscores, pairlist, count, adj);
    soft_nms_finish_kernel<<<dim3(BATCH), dim3(FBLK), 0, stream>>>(
        sboxes, sscores, adj, minx1c, maxx2c, boxes_raw, d_out);
}

// Round 20
// 119.908 us; speedup vs baseline: 1.1549x; 1.1549x over previous
//
#include <hip/hip_runtime.h>
#include <hip/hip_bf16.h>

#define BATCH   4
#define NBOX    8192
#define BLOCK   256
#define TSZ     256                  // tile size (rows & cols)
#define NT      (NBOX / TSZ)         // 32 tiles per batch
#define NPAIRS  (NT * (NT + 1) / 2)  // 528 tile-pairs per batch
#define NBINS   2048
#define SUBS    8                    // sub-slices per batch for the sort
#define SUBSZ   (NBOX / SUBS)        // 1024 boxes per slice
#define STH     512                  // sort kernel threads

__device__ __forceinline__ float bf2f(unsigned short u) {
    union { unsigned int i; float f; } c;
    c.i = ((unsigned int)u) << 16;
    return c.f;
}

__device__ __forceinline__ bool box_plausible(float x1, float y1, float x2, float y2) {
    bool ok = (x1 == x1) && (y1 == y1) && (x2 == x2) && (y2 == y2);
    ok = ok && fabsf(x1) < 1e4f && fabsf(y1) < 1e4f && fabsf(x2) < 1e4f && fabsf(y2) < 1e4f;
    ok = ok && x1 >= -1.0f && x1 <= 300.0f && y1 >= -1.0f && y1 <= 300.0f;
    const float w = x2 - x1, h = y2 - y1;
    ok = ok && w >= -0.1f && w <= 80.0f && h >= -0.1f && h <= 80.0f;
    return ok;
}

// Wave-redundant dtype probe; all waves deterministically agree. true -> f32.
__device__ __forceinline__ bool wave_probe_is_f32(const void* boxes_raw) {
    const int lane = threadIdx.x & 63;
    const float* bf = (const float*)boxes_raw;
    const bool okf = box_plausible(bf[lane * 4 + 0], bf[lane * 4 + 1],
                                   bf[lane * 4 + 2], bf[lane * 4 + 3]);
    const unsigned short* bh = (const unsigned short*)boxes_raw;
    const bool okh = box_plausible(bf2f(bh[lane * 4 + 0]), bf2f(bh[lane * 4 + 1]),
                                   bf2f(bh[lane * 4 + 2]), bf2f(bh[lane * 4 + 3]));
    const unsigned long long mf = __ballot(okf);
    const unsigned long long mh = __ballot(okh);
    return __popcll(mf) >= __popcll(mh);
}

__device__ __forceinline__ float4 load_box(const void* boxes_raw, size_t idx, bool isf32) {
    if (isf32) {
        return reinterpret_cast<const float4*>(boxes_raw)[idx];
    } else {
        const ushort4 u = reinterpret_cast<const ushort4*>(boxes_raw)[idx];
        return make_float4(bf2f(u.x), bf2f(u.y), bf2f(u.z), bf2f(u.w));
    }
}

__device__ __forceinline__ float load_score(const void* scores_raw, size_t idx, bool isf32) {
    return isf32 ? ((const float*)scores_raw)[idx]
                 : bf2f(((const unsigned short*)scores_raw)[idx]);
}

__device__ __forceinline__ int x1_bin(float x1) {
    const int bb = (int)(x1 * 8.0f);           // 2048 bins over [0,256)
    return min(NBINS - 1, max(0, bb));
}

// exp(-iou/0.5) = exp2(iou * (-2 log2 e)); arg in [-2.886, 0] -> raw v_exp ok
#define CEXP (-2.8853900817779268f)

__device__ __forceinline__ float pair_weight(
    float ix1, float iy1, float ix2, float iy2, float iarea,
    const float4& bj, float jarea)
{
    float w = fminf(ix2, bj.z) - fmaxf(ix1, bj.x);
    float h = fminf(iy2, bj.w) - fmaxf(iy1, bj.y);
    w = fmaxf(w, 0.0f);
    h = fmaxf(h, 0.0f);
    const float inter = w * h;
    const float uni   = iarea + jarea - inter;          // >= ~1 always
    const float arg   = (CEXP * inter) * __builtin_amdgcn_rcpf(uni);
    return __builtin_amdgcn_exp2f(arg);
}

// Single fused sort kernel (32 blocks, 512 threads). Every block REDUNDANTLY
// histograms the full batch (deterministic -> identical in all blocks), which
// removes the cross-block scan dependency that would force 2 dispatches. Also
// builds per-bin max-x2 (LDS atomicMax on float bits; coords > 0 -> monotone)
// giving near-exact tile meta. sub==0 blocks publish meta + the compacted
// live pair list. [r15 configuration — measured best, 120.8 us total]
__global__ __launch_bounds__(STH) void sort_kernel(
    const void* __restrict__ boxes_raw, const void* __restrict__ scores_raw,
    float4* __restrict__ sboxes, float* __restrict__ sscores,
    float* __restrict__ adj,                                  // (B,N) zeroed
    float* __restrict__ minx1c, float* __restrict__ maxx2c,   // (B,NT)
    int* __restrict__ pairlist, int* __restrict__ count)      // (B,NPAIRS),(B)
{
    __shared__ int hist[NBINS];          // full-batch counts -> then sex
    __shared__ int bmax[NBINS];          // per-bin max x2 bits
    __shared__ int hist2[NBINS];         // earlier-subs counts -> then loff
    __shared__ int wsum[STH / 64];
    __shared__ float sminT[NT], smaxT[NT];
    __shared__ int scnt;

    const int b    = blockIdx.x / SUBS;
    const int sub  = blockIdx.x % SUBS;
    const int tid  = threadIdx.x;
    const int lane = tid & 63;
    const int wv   = tid >> 6;
    const bool isf32 = wave_probe_is_f32(boxes_raw);
    const size_t base = (size_t)b * NBOX;

#pragma unroll
    for (int i = 0; i < NBINS / STH; i++) {
        hist[i * STH + tid]  = 0;
        bmax[i * STH + tid]  = 0;
        hist2[i * STH + tid] = 0;
    }
    if (tid == 0) scnt = 0;
    {   // zero adj: 32 blocks x 1024 floats covers B*NBOX
        const size_t z = (size_t)blockIdx.x * 1024;
        adj[z + tid] = 0.0f;
        adj[z + STH + tid] = 0.0f;
    }
    __syncthreads();

    // full-batch histogram + per-bin max x2 (identical in every block)
#pragma unroll
    for (int k = 0; k < NBOX / STH; k++) {
        const float4 bx = load_box(boxes_raw, base + k * STH + tid, isf32);
        const int bin = x1_bin(bx.x);
        atomicAdd(&hist[bin], 1);
        atomicMax(&bmax[bin], __float_as_int(bx.z));
    }
    // earlier-subs histogram for my private scatter offsets
    for (int i = tid; i < sub * SUBSZ; i += STH) {
        const float4 bx = load_box(boxes_raw, base + i, isf32);
        atomicAdd(&hist2[x1_bin(bx.x)], 1);
    }
    __syncthreads();

    // exclusive scan of hist: 4 bins/thread + wave shfl scan + cross-wave
    {
        int tot[4], cum[4];
        int run = 0;
#pragma unroll
        for (int i = 0; i < 4; i++) {
            tot[i] = hist[tid * 4 + i];
            run += tot[i]; cum[i] = run;
        }
        int v = run;
#pragma unroll
        for (int d = 1; d < 64; d <<= 1) {
            const int u = __shfl_up(v, d);
            if (lane >= d) v += u;
        }
        if (lane == 63) wsum[wv] = v;
        __syncthreads();
        int wb = 0;
        for (int w = 0; w < wv; w++) wb += wsum[w];
        const int tb = wb + v - run;                 // exclusive thread base
#pragma unroll
        for (int i = 0; i < 4; i++) {
            const int bin = tid * 4 + i;
            const int e = tb + cum[i] - tot[i];      // exclusive bin start
            const int m = hist2[bin];                // my-sub prefix in bin
            hist[bin]  = e;                          // sex (own bins only)
            hist2[bin] = e + m;                      // loff (own bins only)
        }
    }
    __syncthreads();

    // tile meta: binary search on sex (nondecreasing, sex[0]==0); near-exact
    // maxx2 from bmax over the tile's bin range. Identical in every block.
    if (tid < NT) {
        int p = tid * TSZ;
        int lo = 0, hi = NBINS - 1;
        while (lo < hi) { const int mid = (lo + hi + 1) >> 1;
                          if (hist[mid] <= p) lo = mid; else hi = mid - 1; }
        const int Bf = lo;
        p = tid * TSZ + TSZ - 1;
        lo = 0; hi = NBINS - 1;
        while (lo < hi) { const int mid = (lo + hi + 1) >> 1;
                          if (hist[mid] <= p) lo = mid; else hi = mid - 1; }
        const int Bl = lo;
        int mb = 0;
        for (int q = Bf; q <= Bl; q++) mb = max(mb, bmax[q]);
        const float mn = (float)Bf * 0.125f;         // lower bound of tile min x1
        const float mx = __int_as_float(mb);         // upper bound of tile max x2
        sminT[tid] = mn; smaxT[tid] = mx;
        if (sub == 0) {
            minx1c[b * NT + tid] = mn;
            maxx2c[b * NT + tid] = mx;
        }
    }
    __syncthreads();

    // compacted live pair list (sub==0 only; same compares finish will use)
    if (sub == 0) {
        for (int q = tid; q < NPAIRS; q += STH) {
            int p = q, it = 0;
            while (p >= NT - it) { p -= NT - it; it++; }
            const int jt = it + p;
            const bool live = !((smaxT[it] < sminT[jt]) || (smaxT[jt] < sminT[it]));
            if (live) {
                const int idx = atomicAdd(&scnt, 1);
                pairlist[b * NPAIRS + idx] = (it << 8) | jt;
            }
        }
    }

    // scatter my slice
#pragma unroll
    for (int k = 0; k < SUBSZ / STH; k++) {
        const int i = sub * SUBSZ + k * STH + tid;
        const float4 bx = load_box(boxes_raw, base + i, isf32);
        const float  sc = load_score(scores_raw, base + i, isf32);
        const int pos = atomicAdd(&hist2[x1_bin(bx.x)], 1);
        sboxes[base + pos]  = bx;
        sscores[base + pos] = sc;
    }

    __syncthreads();
    if (sub == 0 && tid == 0) count[b] = scnt;
}

// adj over live tile-pairs only (round-7 hot loop at its VALU-issue roofline).
// Live blocks are compacted at the grid front; dead blocks exit on one load.
__global__ __launch_bounds__(BLOCK, 4) void soft_nms_adj_kernel(
    const float4* __restrict__ sboxes,   // (B,N) sorted f32 boxes
    const float* __restrict__ sscores,   // (B,N) sorted f32 scores
    const int* __restrict__ pairlist,    // (B,NPAIRS) compacted live pairs
    const int* __restrict__ count,       // (B)
    float* __restrict__ adj)             // (B,N) f32, zeroed
{
    __shared__ float4 sbox[TSZ];          // j-tile: x1,y1,x2,y2
    __shared__ float2 sas[TSZ];           // j-tile: area, score
    __shared__ float  srow[4][TSZ];       // per-wave row partials

    const int bid = blockIdx.x;
    const int b   = bid / NPAIRS;
    const int p   = bid % NPAIRS;
    if (p >= count[b]) return;            // dead block: one scalar load
    const int pr = pairlist[b * NPAIRS + p];
    const int it = pr >> 8, jt = pr & 255;

    const int tid  = threadIdx.x;
    const int lane = tid & 63;
    const int wv   = tid >> 6;
    const size_t base = (size_t)b * NBOX;

    // stage j-tile into LDS
    {
        const int jg = jt * TSZ + tid;
        const float4 uj = sboxes[base + jg];
        sbox[tid] = uj;
        sas[tid]  = make_float2((uj.z - uj.x) * (uj.w - uj.y), sscores[base + jg]);
    }

    // rows: thread owns rows {k*64 + lane} of the i-tile (same set in every wave)
    float rx1[4], ry1[4], rx2[4], ry2[4], rar[4], rsc[4], accr[4];
#pragma unroll
    for (int k = 0; k < 4; k++) {
        const int ig = it * TSZ + k * 64 + lane;
        const float4 ui = sboxes[base + ig];
        rx1[k] = ui.x; ry1[k] = ui.y; rx2[k] = ui.z; ry2[k] = ui.w;
        rar[k] = (ui.z - ui.x) * (ui.w - ui.y);
        rsc[k] = sscores[base + ig];
        accr[k] = 0.0f;
    }

    __syncthreads();

    const int wvbase = wv * 64;

    if (it == jt) {
        // diagonal: full ordered pairs, row side only (includes i==j)
#pragma unroll 2
        for (int t = 0; t < 64; t++) {
            const int idx = wvbase + ((lane + t) & 63);
            const float4 bj = sbox[idx];
            const float2 as = sas[idx];
#pragma unroll
            for (int k = 0; k < 4; k++) {
                const float e = pair_weight(rx1[k], ry1[k], rx2[k], ry2[k], rar[k], bj, as.x);
                accr[k] = fmaf(e, as.y, accr[k]);
            }
        }
    } else {
        // off-diagonal: symmetric; col accumulator rides in registers per lane
        float accc = 0.0f;
#pragma unroll 2
        for (int t = 0; t < 64; t++) {
            const int idx = wvbase + ((lane + t) & 63);
            const float4 bj = sbox[idx];       // stride-1 window: conflict-free
            const float2 as = sas[idx];
            const float e0 = pair_weight(rx1[0], ry1[0], rx2[0], ry2[0], rar[0], bj, as.x);
            const float e1 = pair_weight(rx1[1], ry1[1], rx2[1], ry2[1], rar[1], bj, as.x);
            const float e2 = pair_weight(rx1[2], ry1[2], rx2[2], ry2[2], rar[2], bj, as.x);
            const float e3 = pair_weight(rx1[3], ry1[3], rx2[3], ry2[3], rar[3], bj, as.x);
            accr[0] = fmaf(e0, as.y, accr[0]);
            accr[1] = fmaf(e1, as.y, accr[1]);
            accr[2] = fmaf(e2, as.y, accr[2]);
            accr[3] = fmaf(e3, as.y, accr[3]);
            const float c = fmaf(e0, rsc[0], fmaf(e1, rsc[1], fmaf(e2, rsc[2], e3 * rsc[3])));
            accc += __shfl(c, (lane - t) & 63);    // owner lane (lane+t)&63 pulls
        }
        atomicAdd(&adj[base + jt * TSZ + wvbase + lane], accc);  // exclusive window
    }

    // combine row partials across the 4 waves via LDS, one atomic per row
#pragma unroll
    for (int k = 0; k < 4; k++) srow[wv][k * 64 + lane] = accr[k];
    __syncthreads();
    {
        const float rs = srow[0][tid] + srow[1][tid] + srow[2][tid] + srow[3][tid];
        atomicAdd(&adj[base + it * TSZ + tid], rs);
    }
}

// finish: skipped-pair ssum correction from the SAME meta arrays, then
// softmax(adjusted) + weighted box sum -> 4 outputs.
#define FBLK 1024
__global__ __launch_bounds__(FBLK) void soft_nms_finish_kernel(
    const float4* __restrict__ sboxes,   // (B,N) sorted f32 boxes
    const float* __restrict__ sscores,   // (B,N) sorted f32 scores
    const float* __restrict__ adj,       // (B,N) f32
    const float* __restrict__ minx1c, const float* __restrict__ maxx2c,  // (B,NT)
    const void* __restrict__ boxes_raw,  // only for output-dtype probe
    void* __restrict__ out)              // (B,4) dtype matches input
{
    constexpr int K  = NBOX / FBLK;             // 8 items per thread
    constexpr int NW = FBLK / 64;               // 16 waves
    __shared__ float sminx[NT], smaxx[NT], ssumT[NT], scorr[NT];
    __shared__ float smax_[NW];
    __shared__ float sred[NW][5];

    const int b    = blockIdx.x;
    const int tid  = threadIdx.x;
    const int lane = tid & 63;
    const int wv   = tid >> 6;
    const size_t base = (size_t)b * NBOX;

    const bool isf32 = wave_probe_is_f32(boxes_raw);

    if (tid < NT) {
        sminx[tid] = minx1c[b * NT + tid];
        smaxx[tid] = maxx2c[b * NT + tid];
    }
    // per-tile score sums: wave wv covers tiles 2wv, 2wv+1
#pragma unroll
    for (int tt = 0; tt < 2; tt++) {
        const int T = wv * 2 + tt;
        float sm = 0.0f;
#pragma unroll
        for (int q = 0; q < 4; q++) sm += sscores[base + T * TSZ + q * 64 + lane];
#pragma unroll
        for (int off = 32; off > 0; off >>= 1) sm += __shfl_down(sm, off);
        if (lane == 0) ssumT[T] = sm;
    }
    __syncthreads();
    if (tid < NT) {
        float c = 0.0f;
        for (int T2 = 0; T2 < NT; T2++) {
            const bool skip = (smaxx[tid] < sminx[T2]) || (smaxx[T2] < sminx[tid]);
            if (skip) c += ssumT[T2];
        }
        scorr[tid] = c;
    }
    __syncthreads();

    float av[K];
    float m = -3.4e38f;
#pragma unroll
    for (int k = 0; k < K; k++) {
        const int r = k * FBLK + tid;
        av[k] = adj[base + r] + scorr[r >> 8];
        m = fmaxf(m, av[k]);
    }
#pragma unroll
    for (int off = 32; off > 0; off >>= 1)
        m = fmaxf(m, __shfl_down(m, off));
    if (lane == 0) smax_[wv] = m;
    __syncthreads();
    float M = smax_[0];
#pragma unroll
    for (int w = 1; w < NW; w++) M = fmaxf(M, smax_[w]);

    const float L2E = 1.4426950408889634f;
    float es = 0.0f, s0 = 0.0f, s1 = 0.0f, s2 = 0.0f, s3 = 0.0f;
#pragma unroll
    for (int k = 0; k < K; k++) {
        const float e = __builtin_amdgcn_exp2f((av[k] - M) * L2E);
        const float4 u = sboxes[base + k * FBLK + tid];
        es += e;
        s0 += e * u.x;
        s1 += e * u.y;
        s2 += e * u.z;
        s3 += e * u.w;
    }
#pragma unroll
    for (int off = 32; off > 0; off >>= 1) {
        es += __shfl_down(es, off);
        s0 += __shfl_down(s0, off);
        s1 += __shfl_down(s1, off);
        s2 += __shfl_down(s2, off);
        s3 += __shfl_down(s3, off);
    }
    if (lane == 0) {
        sred[wv][0] = es; sred[wv][1] = s0; sred[wv][2] = s1;
        sred[wv][3] = s2; sred[wv][4] = s3;
    }
    __syncthreads();
    if (tid == 0) {
        float ES = 0.0f, o[4] = {0.0f, 0.0f, 0.0f, 0.0f};
#pragma unroll
        for (int w = 0; w < NW; w++) {
            ES   += sred[w][0];
            o[0] += sred[w][1];
            o[1] += sred[w][2];
            o[2] += sred[w][3];
            o[3] += sred[w][4];
        }
        const float inv = 1.0f / ES;
        if (isf32) {
            float* of = (float*)out;
            for (int c = 0; c < 4; c++) of[b * 4 + c] = o[c] * inv;
        } else {
            __hip_bfloat16* oh = (__hip_bfloat16*)out;
            for (int c = 0; c < 4; c++) oh[b * 4 + c] = __float2bfloat16(o[c] * inv);
        }
    }
}

extern "C" void kernel_launch(void* const* d_in, const int* in_sizes, int n_in,
                              void* d_out, int out_size, void* d_ws, size_t ws_size,
                              hipStream_t stream) {
    const void* boxes_raw  = d_in[0];   // (4,8192,4)
    const void* scores_raw = d_in[1];   // (4,8192)

    char* w = (char*)d_ws;
    float4* sboxes   = (float4*)w;                 w += (size_t)BATCH * NBOX * 16;
    float*  sscores  = (float*)w;                  w += (size_t)BATCH * NBOX * 4;
    float*  adj      = (float*)w;                  w += (size_t)BATCH * NBOX * 4;
    float*  minx1c   = (float*)w;                  w += (size_t)BATCH * NT * 4;
    float*  maxx2c   = (float*)w;                  w += (size_t)BATCH * NT * 4;
    int*    pairlist = (int*)w;                    w += (size_t)BATCH * NPAIRS * 4;
    int*    count    = (int*)w;

    sort_kernel<<<dim3(BATCH * SUBS), dim3(STH), 0, stream>>>(
        boxes_raw, scores_raw, sboxes, sscores, adj, minx1c, maxx2c, pairlist, count);
    soft_nms_adj_kernel<<<dim3(BATCH * NPAIRS), dim3(BLOCK), 0, stream>>>(
        sboxes, sscores, pairlist, count, adj);
    soft_nms_finish_kernel<<<dim3(BATCH), dim3(FBLK), 0, stream>>>(
        sboxes, sscores, adj, minx1c, maxx2c, boxes_raw, d_out);
}